// Round 1
// baseline (380.450 us; speedup 1.0000x reference)
//
#include <hip/hip_runtime.h>
#include <math.h>

#define BB 4
#define TT 1024
#define FIN 256
#define DD 128
#define CL 16              // chunk length
#define NC 64              // chunks = TT/CL
#define ROWS (BB*TT)       // 4096

// ---------------------------------------------------------------------------
// Kernel 1: LayerNorm + 4 GEMMs (K,Q with phi=elu+1; V plain; XS = xn@Ws^T+bs)
// grid 512 x 256 threads, 8 rows/block.
// ---------------------------------------------------------------------------
__global__ __launch_bounds__(256) void k_ln_qkv(
    const float* __restrict__ x, const float* __restrict__ gamma, const float* __restrict__ beta,
    const float* __restrict__ Wk, const float* __restrict__ Wq, const float* __restrict__ Wv,
    const float* __restrict__ Ws, const float* __restrict__ bs,
    float* __restrict__ Kp, float* __restrict__ Qp, float* __restrict__ Vp, float* __restrict__ XSp)
{
    __shared__ float xt[8][FIN];
    const int tid  = threadIdx.x;
    const int row0 = blockIdx.x * 8;

    // ---- LayerNorm: 32 threads per row, 8 elements per thread ----
    {
        const int r = tid >> 5, l = tid & 31;
        const float* xr = x + (size_t)(row0 + r) * FIN + l * 8;
        float v[8];
        #pragma unroll
        for (int k = 0; k < 8; ++k) v[k] = xr[k];
        float s = 0.f, sq = 0.f;
        #pragma unroll
        for (int k = 0; k < 8; ++k) { s += v[k]; sq += v[k] * v[k]; }
        #pragma unroll
        for (int m = 16; m >= 1; m >>= 1) {
            s  += __shfl_xor(s,  m, 64);
            sq += __shfl_xor(sq, m, 64);
        }
        const float mu  = s * (1.0f / FIN);
        const float var = sq * (1.0f / FIN) - mu * mu;
        const float rs  = rsqrtf(var + 1e-5f);
        #pragma unroll
        for (int k = 0; k < 8; ++k) {
            const int f = l * 8 + k;
            xt[r][f] = (v[k] - mu) * rs * gamma[f] + beta[f];
        }
    }
    __syncthreads();

    // ---- GEMM: thread computes 2 output columns (one of K/Q, one of V/XS) ----
    const int m0 = tid >> 7;            // 0 -> K, 1 -> Q
    const int d  = tid & 127;
    const int m1 = (tid + 256) >> 7;    // 2 -> V, 3 -> XS
    const float* W0 = (m0 == 0 ? Wk : Wq) + (size_t)d * FIN;
    const float* W1r = (m1 == 2 ? Wv : Ws) + (size_t)d * FIN;

    float acc0[8], acc1[8];
    #pragma unroll
    for (int r = 0; r < 8; ++r) { acc0[r] = 0.f; acc1[r] = 0.f; }

    for (int k4 = 0; k4 < FIN / 4; ++k4) {
        const float4 w0 = ((const float4*)W0)[k4];
        const float4 w1 = ((const float4*)W1r)[k4];
        #pragma unroll
        for (int r = 0; r < 8; ++r) {
            const float4 xv = ((const float4*)xt[r])[k4];
            acc0[r] += w0.x * xv.x + w0.y * xv.y + w0.z * xv.z + w0.w * xv.w;
            acc1[r] += w1.x * xv.x + w1.y * xv.y + w1.z * xv.z + w1.w * xv.w;
        }
    }

    float* dst0 = (m0 == 0 ? Kp : Qp);
    float* dst1 = (m1 == 2 ? Vp : XSp);
    const float bsv = (m1 == 3) ? bs[d] : 0.f;
    #pragma unroll
    for (int r = 0; r < 8; ++r) {
        float a = acc0[r];
        a = (a > 0.f) ? (a + 1.f) : expf(a);          // phi = elu+1
        dst0[(size_t)(row0 + r) * DD + d] = a;
        dst1[(size_t)(row0 + r) * DD + d] = acc1[r] + bsv;
    }
}

// ---------------------------------------------------------------------------
// Kernel 2: per-chunk sums  sumKV[b,c,i,j] = sum_t K[t,i]V[t,j], sumK[b,c,i]
// grid 256 (b*c) x 256 threads
// ---------------------------------------------------------------------------
__global__ __launch_bounds__(256) void k_chunksum(
    const float* __restrict__ Kp, const float* __restrict__ Vp,
    float* __restrict__ SKV, float* __restrict__ SK)
{
    __shared__ float Kb[CL][DD];
    __shared__ float Vb[CL][DD];
    const int tid = threadIdx.x;
    const int c = blockIdx.x & (NC - 1);
    const int b = blockIdx.x >> 6;
    const size_t base = (size_t)(b * TT + c * CL) * DD;

    #pragma unroll
    for (int q = 0; q < 2; ++q) {
        const int fi = q * 256 + tid;     // float4 index 0..511
        ((float4*)&Kb[0][0])[fi] = ((const float4*)(Kp + base))[fi];
        ((float4*)&Vb[0][0])[fi] = ((const float4*)(Vp + base))[fi];
    }
    __syncthreads();

    const int j = tid & 127, hi = tid >> 7;
    float acc[64];
    #pragma unroll
    for (int w = 0; w < 64; ++w) acc[w] = 0.f;

    for (int t = 0; t < CL; ++t) {
        const float vj = Vb[t][j];
        #pragma unroll
        for (int w4 = 0; w4 < 16; ++w4) {
            const float4 kf = *(const float4*)&Kb[t][hi * 64 + w4 * 4];
            acc[w4 * 4 + 0] += kf.x * vj;
            acc[w4 * 4 + 1] += kf.y * vj;
            acc[w4 * 4 + 2] += kf.z * vj;
            acc[w4 * 4 + 3] += kf.w * vj;
        }
    }

    float* out = SKV + (size_t)(b * NC + c) * DD * DD;
    #pragma unroll
    for (int w = 0; w < 64; ++w) {
        const int i = hi * 64 + w;
        out[(size_t)i * DD + j] = acc[w];
    }
    if (tid < DD) {
        float s = 0.f;
        #pragma unroll
        for (int t = 0; t < CL; ++t) s += Kb[t][tid];
        SK[(size_t)(b * NC + c) * DD + tid] = s;
    }
}

// ---------------------------------------------------------------------------
// Kernel 3: prefix over chunks -> writes chunk-END slices of S and Z outputs
// grid 256 x 256 (one thread per (b,i,j))
// ---------------------------------------------------------------------------
__global__ __launch_bounds__(256) void k_prefix(
    const float* __restrict__ SKV, const float* __restrict__ SK,
    const float* __restrict__ S0, const float* __restrict__ Z0,
    float* __restrict__ Sout, float* __restrict__ Zout)
{
    const int gid = blockIdx.x * 256 + threadIdx.x;   // 0..65535
    const int b = gid >> 14, e = gid & 16383;
    float acc = S0[(size_t)b * 16384 + e];
    const float* p = SKV + (size_t)b * NC * 16384 + e;
    float* so = Sout + (size_t)b * TT * 16384 + (size_t)(CL - 1) * 16384 + e;
    for (int c = 0; c < NC; ++c) {
        acc += p[(size_t)c * 16384];
        so[(size_t)c * CL * 16384] = acc;
    }
    if (gid < BB * DD) {
        const int b2 = gid >> 7, i = gid & 127;
        float z = Z0[b2 * DD + i];
        for (int c = 0; c < NC; ++c) {
            z += SK[(size_t)(b2 * NC + c) * DD + i];
            Zout[(size_t)(b2 * TT + c * CL + CL - 1) * DD + i] = z;
        }
    }
}

// ---------------------------------------------------------------------------
// Kernel 4: intra-chunk scan. block = (b, chunk, column-half). State 128x64 in
// registers (32 floats/thread). Writes S rows (t < CL-1), Z, and NUM = Q.S.
// grid 512 x 256 threads
// ---------------------------------------------------------------------------
__global__ __launch_bounds__(256) void k_scan(
    const float* __restrict__ Kp, const float* __restrict__ Qp, const float* __restrict__ Vp,
    const float* __restrict__ S0, const float* __restrict__ Z0,
    float* __restrict__ Sout, float* __restrict__ Zout, float* __restrict__ NUM)
{
    __shared__ float Kb[CL][DD];
    __shared__ float Qb[CL][DD];
    __shared__ float Vb[CL][64];
    __shared__ float4 nred[2][4][16];

    const int tid  = threadIdx.x;
    const int half = blockIdx.x & 1;
    const int c    = (blockIdx.x >> 1) & (NC - 1);
    const int b    = blockIdx.x >> 7;
    const int j0   = half * 64;
    const size_t rbase = (size_t)(b * TT + c * CL);

    {   // stage K,Q (full) + V slice
        const float4* Ksrc = (const float4*)(Kp + rbase * DD);
        const float4* Qsrc = (const float4*)(Qp + rbase * DD);
        #pragma unroll
        for (int q = 0; q < 2; ++q) {
            const int fi = q * 256 + tid;
            ((float4*)&Kb[0][0])[fi] = Ksrc[fi];
            ((float4*)&Qb[0][0])[fi] = Qsrc[fi];
        }
        const int tv = tid >> 4, gv = tid & 15;
        ((float4*)&Vb[0][0])[tid] = *(const float4*)(Vp + (rbase + tv) * DD + j0 + gv * 4);
    }

    const int g = tid & 15, h = tid >> 4;   // g: j-quad, h: i-group
    float4 acc[8];
    {   // init state from S0 (c==0) or chunk-end slice written by k_prefix
        const float* src = (c == 0) ? (S0 + (size_t)b * 16384)
                                    : (Sout + ((size_t)(b * TT) + c * CL - 1) * 16384);
        #pragma unroll
        for (int w = 0; w < 8; ++w) {
            const int i = w * 16 + h;
            acc[w] = *(const float4*)(src + (size_t)i * DD + j0 + g * 4);
        }
    }
    float zacc = 0.f;
    const bool doZ = (half == 0) && (tid < DD);
    if (doZ) {
        zacc = (c == 0) ? Z0[b * DD + tid]
                        : Zout[((size_t)(b * TT) + c * CL - 1) * DD + tid];
    }
    __syncthreads();

    const int wav = tid >> 6;
    for (int t = 0; t < CL; ++t) {
        const size_t tt = rbase + t;
        const float4 v4 = *(const float4*)&Vb[t][g * 4];
        float4 np; np.x = np.y = np.z = np.w = 0.f;
        float* srow = Sout + tt * 16384 + j0 + g * 4;
        #pragma unroll
        for (int w = 0; w < 8; ++w) {
            const int i = w * 16 + h;
            const float kk = Kb[t][i];
            const float qq = Qb[t][i];
            acc[w].x += kk * v4.x; acc[w].y += kk * v4.y;
            acc[w].z += kk * v4.z; acc[w].w += kk * v4.w;
            if (t < CL - 1) *(float4*)(srow + (size_t)i * DD) = acc[w];
            np.x += qq * acc[w].x; np.y += qq * acc[w].y;
            np.z += qq * acc[w].z; np.w += qq * acc[w].w;
        }
        // reduce np over the 16 i-groups: xor16+xor32 intra-wave, LDS across waves
        #pragma unroll
        for (int m = 16; m <= 32; m <<= 1) {
            np.x += __shfl_xor(np.x, m, 64);
            np.y += __shfl_xor(np.y, m, 64);
            np.z += __shfl_xor(np.z, m, 64);
            np.w += __shfl_xor(np.w, m, 64);
        }
        if ((tid & 63) < 16) nred[t & 1][wav][g] = np;
        if (doZ) {
            zacc += Kb[t][tid];
            if (t < CL - 1) Zout[tt * DD + tid] = zacc;
        }
        __syncthreads();
        if (tid < 16) {
            const float4 r0 = nred[t & 1][0][tid], r1 = nred[t & 1][1][tid];
            const float4 r2 = nred[t & 1][2][tid], r3 = nred[t & 1][3][tid];
            float4 o;
            o.x = r0.x + r1.x + r2.x + r3.x;
            o.y = r0.y + r1.y + r2.y + r3.y;
            o.z = r0.z + r1.z + r2.z + r3.z;
            o.w = r0.w + r1.w + r2.w + r3.w;
            *(float4*)(NUM + tt * DD + j0 + tid * 4) = o;
        }
    }
}

// ---------------------------------------------------------------------------
// Kernel 5: den = Q.Z + eps, h0 = num/den, 2-layer MLP (relu), + XS residual.
// 256 threads; W1/W2 half-rows register-resident; 16 rows/block; grid 256.
// ---------------------------------------------------------------------------
__global__ __launch_bounds__(256) void k_mlp(
    const float* __restrict__ NUM, const float* __restrict__ Qp,
    const float* __restrict__ Zp, const float* __restrict__ XSp,
    const float* __restrict__ W1, const float* __restrict__ b1,
    const float* __restrict__ W2, const float* __restrict__ b2,
    float* __restrict__ Oout)
{
    __shared__ float h0[16][DD];
    __shared__ float h1[16][DD];
    __shared__ float parr[16][256];
    __shared__ float denl[16];
    const int tid = threadIdx.x;
    const int d = tid & 127, s = tid >> 7;
    const int row0 = blockIdx.x * 16;

    float4 w1r[16], w2r[16];
    #pragma unroll
    for (int k4 = 0; k4 < 16; ++k4) {
        w1r[k4] = *(const float4*)(W1 + (size_t)d * DD + s * 64 + k4 * 4);
        w2r[k4] = *(const float4*)(W2 + (size_t)d * DD + s * 64 + k4 * 4);
    }

    {   // den: 16 threads per row
        const int r = tid >> 4, kk = tid & 15;
        const float* qrow = Qp + (size_t)(row0 + r) * DD + kk * 8;
        const float* zrow = Zp + (size_t)(row0 + r) * DD + kk * 8;
        float sden = 0.f;
        #pragma unroll
        for (int u = 0; u < 8; ++u) sden += qrow[u] * zrow[u];
        #pragma unroll
        for (int m = 1; m <= 8; m <<= 1) sden += __shfl_xor(sden, m, 64);
        if (kk == 0) denl[r] = sden + 1e-5f;
    }
    __syncthreads();

    #pragma unroll
    for (int q = 0; q < 8; ++q) {
        const int f = q * 256 + tid;
        const int r = f >> 7, dd2 = f & 127;
        h0[r][dd2] = NUM[(size_t)row0 * DD + f] / denl[r];
    }
    __syncthreads();

    #pragma unroll
    for (int r = 0; r < 16; ++r) {
        float pp = 0.f;
        #pragma unroll
        for (int k4 = 0; k4 < 16; ++k4) {
            const float4 xv = *(const float4*)&h0[r][s * 64 + k4 * 4];
            pp += w1r[k4].x * xv.x + w1r[k4].y * xv.y + w1r[k4].z * xv.z + w1r[k4].w * xv.w;
        }
        parr[r][tid] = pp;
    }
    __syncthreads();
    #pragma unroll
    for (int q = 0; q < 8; ++q) {
        const int f = q * 256 + tid;
        const int r = f >> 7, dd2 = f & 127;
        h1[r][dd2] = fmaxf(parr[r][dd2] + parr[r][dd2 + 128] + b1[dd2], 0.f);
    }
    __syncthreads();

    #pragma unroll
    for (int r = 0; r < 16; ++r) {
        float pp = 0.f;
        #pragma unroll
        for (int k4 = 0; k4 < 16; ++k4) {
            const float4 xv = *(const float4*)&h1[r][s * 64 + k4 * 4];
            pp += w2r[k4].x * xv.x + w2r[k4].y * xv.y + w2r[k4].z * xv.z + w2r[k4].w * xv.w;
        }
        parr[r][tid] = pp;
    }
    __syncthreads();
    #pragma unroll
    for (int q = 0; q < 8; ++q) {
        const int f = q * 256 + tid;
        const int r = f >> 7, dd2 = f & 127;
        const float hv = fmaxf(parr[r][dd2] + parr[r][dd2 + 128] + b2[dd2], 0.f);
        Oout[(size_t)row0 * DD + f] = hv + XSp[(size_t)row0 * DD + f];
    }
}

// ---------------------------------------------------------------------------
extern "C" void kernel_launch(void* const* d_in, const int* in_sizes, int n_in,
                              void* d_out, int out_size, void* d_ws, size_t ws_size,
                              hipStream_t stream)
{
    const float* x  = (const float*)d_in[0];
    const float* S0 = (const float*)d_in[1];
    const float* Z0 = (const float*)d_in[2];
    const float* g  = (const float*)d_in[3];
    const float* be = (const float*)d_in[4];
    const float* Wk = (const float*)d_in[5];
    const float* Wq = (const float*)d_in[6];
    const float* Wv = (const float*)d_in[7];
    const float* W1 = (const float*)d_in[8];
    const float* b1 = (const float*)d_in[9];
    const float* W2 = (const float*)d_in[10];
    const float* b2 = (const float*)d_in[11];
    const float* Ws = (const float*)d_in[12];
    const float* bs = (const float*)d_in[13];

    float* outp = (float*)d_out;                  // [B,T,D]
    float* Sout = outp + (size_t)ROWS * DD;       // [B,T,D,D]
    float* Zout = Sout + (size_t)BB * TT * DD * DD; // [B,T,D]

    float* ws  = (float*)d_ws;
    float* Kp  = ws;
    float* Qp  = Kp + (size_t)ROWS * DD;
    float* Vp  = Qp + (size_t)ROWS * DD;
    float* XSp = Vp + (size_t)ROWS * DD;
    float* NUM = XSp + (size_t)ROWS * DD;
    float* SKV = NUM + (size_t)ROWS * DD;
    float* SK  = SKV + (size_t)BB * NC * DD * DD;

    k_ln_qkv  <<<ROWS / 8, 256, 0, stream>>>(x, g, be, Wk, Wq, Wv, Ws, bs, Kp, Qp, Vp, XSp);
    k_chunksum<<<BB * NC, 256, 0, stream>>>(Kp, Vp, SKV, SK);
    k_prefix  <<<BB * DD * DD / 256, 256, 0, stream>>>(SKV, SK, S0, Z0, Sout, Zout);
    k_scan    <<<BB * NC * 2, 256, 0, stream>>>(Kp, Qp, Vp, S0, Z0, Sout, Zout, NUM);
    k_mlp     <<<ROWS / 16, 256, 0, stream>>>(NUM, Qp, Zout, XSp, W1, b1, W2, b2, outp);
}